// Round 3
// baseline (3141.418 us; speedup 1.0000x reference)
//
#include <hip/hip_runtime.h>
#include <math.h>

#define BATCH 16
#define CIN   128
#define HID   128
#define HDIM  64
#define WDIM  64
#define HW    (HDIM * WDIM)   // 4096

// ---------------------------------------------------------------------------
// Pack kernel: reorder weights so each wave (= one hid channel) reads small
// contiguous wave-uniform chunks per c (scalar s_loads, parallel to VALU).
//   Wis_p[h][c][g][t2]  (8 floats / c)   taps 0,1 ('B' mask zeroes tap 2)
//   Wss_p[h][c][g][t3]  (12 floats / c)
//   bias_p[h][g] = b_is + b_ss
// Original: W_is/W_ss = [o=g*128+h][c][1][3], b = [512]
// ---------------------------------------------------------------------------
__global__ void pack_kernel(const float* __restrict__ W_is,
                            const float* __restrict__ b_is,
                            const float* __restrict__ W_ss,
                            const float* __restrict__ b_ss,
                            float* __restrict__ Wis_p,
                            float* __restrict__ Wss_p,
                            float* __restrict__ bias_p) {
    int idx = blockIdx.x * blockDim.x + threadIdx.x;

    if (idx < HID * CIN * 4 * 2) {          // ((h*128+c)*4+g)*2+t
        int t = idx & 1;
        int g = (idx >> 1) & 3;
        int c = (idx >> 3) & 127;
        int h = idx >> 10;
        Wis_p[idx] = W_is[((g * HID + h) * CIN + c) * 3 + t];
    }
    if (idx < HID * CIN * 4 * 3) {          // ((h*128+c)*4+g)*3+t
        int t = idx % 3;
        int rest = idx / 3;
        int g = rest & 3;
        int c = (rest >> 2) & 127;
        int h = rest >> 9;
        Wss_p[idx] = W_ss[((g * HID + h) * CIN + c) * 3 + t];
    }
    if (idx < HID * 4) {                    // h*4+g
        int g = idx & 3;
        int h = idx >> 2;
        bias_p[idx] = b_is[g * HID + h] + b_ss[g * HID + h];
    }
}

// ---------------------------------------------------------------------------
// Row kernel v3: one LSTM row step, LDS-staged activations.
// Grid: 512 blocks x 256 threads (4 waves). Block -> (b, 4 hid channels);
// all 4 waves share batch b, so the x-row and h-row are staged ONCE into LDS
// and read back as swizzled ds_read_b128 (4 channels per lane, 2-way banks).
// Per-tap accumulators (linear conv) -> no cross-lane ops in the K-loop;
// 8 shuffles per wave at the end combine taps:
//   z[w] = S0[w-1] + S1[w] + S2[w+1].
// LDS layout: lds[w][c ^ ((w&31)<<2)], stride 128 (16B-aligned quads).
// ---------------------------------------------------------------------------
__global__ __launch_bounds__(256, 2) void row_kernel(
        const float* __restrict__ x,
        const float* __restrict__ Wis_p,
        const float* __restrict__ Wss_p,
        const float* __restrict__ bias_p,
        float* __restrict__ c_state,
        float* __restrict__ out,
        int r) {
    __shared__ float lds_x[WDIM * CIN];   // 32 KB
    __shared__ float lds_h[WDIM * HID];   // 32 KB

    const int t   = threadIdx.x;
    const int w   = t & 63;                        // lane = w
    const int wv  = t >> 6;                        // wave in block, 0..3
    const int b   = blockIdx.x >> 5;               // 0..15
    const int hch = ((blockIdx.x & 31) << 2) + wv; // 0..127
    const int swz = (w & 31) << 2;                 // bank swizzle for [w][c]

    // ---- stage x row r : 8192 floats, 32 dwords/thread ----
    {
        const float* xrow = x + (size_t)b * CIN * HW + (size_t)r * WDIM;
        const int cqb = wv << 2;
#pragma unroll
        for (int p = 0; p < 8; ++p) {
            int c0 = p * 16 + cqb;
            float v0 = xrow[(c0 + 0) * HW + w];
            float v1 = xrow[(c0 + 1) * HW + w];
            float v2 = xrow[(c0 + 2) * HW + w];
            float v3 = xrow[(c0 + 3) * HW + w];
            *(float4*)&lds_x[w * CIN + (c0 ^ swz)] = make_float4(v0, v1, v2, v3);
        }
    }
    // ---- stage h row r-1 ----
    if (r > 0) {
        const float* hrow = out + (size_t)b * HID * HW + (size_t)(r - 1) * WDIM;
        const int cqb = wv << 2;
#pragma unroll
        for (int p = 0; p < 8; ++p) {
            int c0 = p * 16 + cqb;
            float v0 = hrow[(c0 + 0) * HW + w];
            float v1 = hrow[(c0 + 1) * HW + w];
            float v2 = hrow[(c0 + 2) * HW + w];
            float v3 = hrow[(c0 + 3) * HW + w];
            *(float4*)&lds_h[w * CIN + (c0 ^ swz)] = make_float4(v0, v1, v2, v3);
        }
    }
    __syncthreads();

    // acc_u: belongs at w+1 (shfl_up at end); acc_c: center; acc_d: at w-1.
    float acc_u[4] = {0.f, 0.f, 0.f, 0.f};
    float acc_c[4] = {0.f, 0.f, 0.f, 0.f};
    float acc_d[4] = {0.f, 0.f, 0.f, 0.f};

    // ---- input-to-state: taps (t0 -> x[w-1], t1 -> x[w]) ----
    {
        const float* wis = Wis_p + (size_t)hch * CIN * 8;
#pragma unroll 4
        for (int cq = 0; cq < CIN; cq += 4) {
            float4 xv = *(const float4*)&lds_x[w * CIN + (cq ^ swz)];
            const float* wp = wis + cq * 8;
            float xa[4] = {xv.x, xv.y, xv.z, xv.w};
#pragma unroll
            for (int k = 0; k < 4; ++k)
#pragma unroll
                for (int g = 0; g < 4; ++g) {
                    acc_u[g] = fmaf(wp[k * 8 + g * 2 + 0], xa[k], acc_u[g]);
                    acc_c[g] = fmaf(wp[k * 8 + g * 2 + 1], xa[k], acc_c[g]);
                }
        }
    }

    // ---- state-to-state: taps (t0 -> h[w-1], t1 -> h[w], t2 -> h[w+1]) ----
    if (r > 0) {
        const float* wss = Wss_p + (size_t)hch * CIN * 12;
#pragma unroll 4
        for (int cq = 0; cq < CIN; cq += 4) {
            float4 hv = *(const float4*)&lds_h[w * CIN + (cq ^ swz)];
            const float* wp = wss + cq * 12;
            float ha[4] = {hv.x, hv.y, hv.z, hv.w};
#pragma unroll
            for (int k = 0; k < 4; ++k)
#pragma unroll
                for (int g = 0; g < 4; ++g) {
                    acc_u[g] = fmaf(wp[k * 12 + g * 3 + 0], ha[k], acc_u[g]);
                    acc_c[g] = fmaf(wp[k * 12 + g * 3 + 1], ha[k], acc_c[g]);
                    acc_d[g] = fmaf(wp[k * 12 + g * 3 + 2], ha[k], acc_d[g]);
                }
        }
    }

    // ---- combine taps: 2 shuffles per gate ----
    float z[4];
#pragma unroll
    for (int g = 0; g < 4; ++g) {
        float zu = __shfl_up(acc_u[g], 1);    // S0 evaluated at w-1
        if (w == 0) zu = 0.0f;
        float zd = __shfl_down(acc_d[g], 1);  // S2 evaluated at w+1
        if (w == 63) zd = 0.0f;
        z[g] = acc_c[g] + zu + zd + bias_p[hch * 4 + g];
    }

    // ---- LSTM update ----
    float ig = 1.0f / (1.0f + __expf(-z[0]));
    float fg = 1.0f / (1.0f + __expf(-z[1]));
    float og = 1.0f / (1.0f + __expf(-z[2]));
    float gg = tanhf(z[3]);

    size_t cidx = ((size_t)b * HID + hch) * WDIM + w;
    float cold = (r == 0) ? 0.0f : c_state[cidx];
    float cnew = fg * cold + ig * gg;
    c_state[cidx] = cnew;
    out[((size_t)b * HID + hch) * HW + (size_t)r * WDIM + w] = og * tanhf(cnew);
}

extern "C" void kernel_launch(void* const* d_in, const int* in_sizes, int n_in,
                              void* d_out, int out_size, void* d_ws, size_t ws_size,
                              hipStream_t stream) {
    const float* x    = (const float*)d_in[0];
    const float* W_is = (const float*)d_in[1];
    const float* b_is = (const float*)d_in[2];
    const float* W_ss = (const float*)d_in[3];
    const float* b_ss = (const float*)d_in[4];
    float* out = (float*)d_out;
    float* ws  = (float*)d_ws;

    // ws layout (floats): c_state[131072] | Wis_p[131072] | Wss_p[196608] | bias_p[512]
    float* c_state = ws;
    float* Wis_p   = ws + 131072;
    float* Wss_p   = ws + 131072 + 131072;
    float* bias_p  = ws + 131072 + 131072 + 196608;

    pack_kernel<<<(HID * CIN * 4 * 3 + 255) / 256, 256, 0, stream>>>(
        W_is, b_is, W_ss, b_ss, Wis_p, Wss_p, bias_p);

    for (int r = 0; r < HDIM; ++r) {
        row_kernel<<<512, 256, 0, stream>>>(
            x, Wis_p, Wss_p, bias_p, c_state, out, r);
    }
}

// Round 4
// 1211.791 us; speedup vs baseline: 2.5924x; 2.5924x over previous
//
#include <hip/hip_runtime.h>
#include <math.h>

#define BATCH 16
#define CIN   128
#define HID   128
#define HDIM  64
#define WDIM  64
#define HW    (HDIM * WDIM)   // 4096

// ---------------------------------------------------------------------------
// Pack kernel: reorder weights so each wave (= one hid channel) reads small
// contiguous wave-uniform chunks per c (scalar s_loads, parallel to VALU).
//   Wis_p[h][c][g][t2]  (8 floats / c)   taps 0,1 ('B' mask zeroes tap 2)
//   Wss_p[h][c][g][t3]  (12 floats / c)
//   bias_p[h][g] = b_is + b_ss
// Original: W_is/W_ss = [o=g*128+h][c][1][3], b = [512]
// ---------------------------------------------------------------------------
__global__ void pack_kernel(const float* __restrict__ W_is,
                            const float* __restrict__ b_is,
                            const float* __restrict__ W_ss,
                            const float* __restrict__ b_ss,
                            float* __restrict__ Wis_p,
                            float* __restrict__ Wss_p,
                            float* __restrict__ bias_p) {
    int idx = blockIdx.x * blockDim.x + threadIdx.x;

    if (idx < HID * CIN * 4 * 2) {          // ((h*128+c)*4+g)*2+t
        int t = idx & 1;
        int g = (idx >> 1) & 3;
        int c = (idx >> 3) & 127;
        int h = idx >> 10;
        Wis_p[idx] = W_is[((g * HID + h) * CIN + c) * 3 + t];
    }
    if (idx < HID * CIN * 4 * 3) {          // ((h*128+c)*4+g)*3+t
        int t = idx % 3;
        int rest = idx / 3;
        int g = rest & 3;
        int c = (rest >> 2) & 127;
        int h = rest >> 9;
        Wss_p[idx] = W_ss[((g * HID + h) * CIN + c) * 3 + t];
    }
    if (idx < HID * 4) {                    // h*4+g
        int g = idx & 3;
        int h = idx >> 2;
        bias_p[idx] = b_is[g * HID + h] + b_ss[g * HID + h];
    }
}

// ---------------------------------------------------------------------------
// Row kernel v4 = v3's LDS staging + v2's scalar (readfirstlane) weights.
// Grid: 512 blocks x 256 threads. Block -> (b, 4 hid channels); the 4 waves
// share batch b, so x-row and h-row are staged ONCE into LDS (coalesced
// global loads) and read back as swizzled ds_read_b128.
// hch goes through readfirstlane so ALL weight reads are SGPR-addressed
// s_loads (v3 regression: without this they become per-lane VMEM loads,
// VGPR 28->128, vmcnt stalls -> 1.7x slower).
// Per-tap accumulators (conv is linear) -> no cross-lane ops in the K-loop;
// 8 shuffles at the end: z[w] = S0[w-1] + S1[w] + S2[w+1].
// ---------------------------------------------------------------------------
__global__ __launch_bounds__(256, 2) void row_kernel(
        const float* __restrict__ x,
        const float* __restrict__ Wis_p,
        const float* __restrict__ Wss_p,
        const float* __restrict__ bias_p,
        float* __restrict__ c_state,
        float* __restrict__ out,
        int r) {
    __shared__ float lds_x[WDIM * CIN];   // 32 KB
    __shared__ float lds_h[WDIM * HID];   // 32 KB

    const int t   = threadIdx.x;
    const int w   = t & 63;                        // lane = w
    const int wv  = t >> 6;                        // wave in block, 0..3
    const int b   = blockIdx.x >> 5;               // 0..15 (scalar)
    const int hch = __builtin_amdgcn_readfirstlane(((blockIdx.x & 31) << 2) + wv);
    const int swz = (w & 31) << 2;                 // bank swizzle for [w][c]

    // ---- stage x row r : 8192 floats, 32 dwords/thread, coalesced ----
    {
        const float* xrow = x + (size_t)b * CIN * HW + (size_t)r * WDIM;
        const int cqb = wv << 2;
#pragma unroll
        for (int p = 0; p < 8; ++p) {
            int c0 = p * 16 + cqb;
            float v0 = xrow[(c0 + 0) * HW + w];
            float v1 = xrow[(c0 + 1) * HW + w];
            float v2 = xrow[(c0 + 2) * HW + w];
            float v3 = xrow[(c0 + 3) * HW + w];
            *(float4*)&lds_x[w * CIN + (c0 ^ swz)] = make_float4(v0, v1, v2, v3);
        }
    }
    // ---- stage h row r-1 ----
    if (r > 0) {
        const float* hrow = out + (size_t)b * HID * HW + (size_t)(r - 1) * WDIM;
        const int cqb = wv << 2;
#pragma unroll
        for (int p = 0; p < 8; ++p) {
            int c0 = p * 16 + cqb;
            float v0 = hrow[(c0 + 0) * HW + w];
            float v1 = hrow[(c0 + 1) * HW + w];
            float v2 = hrow[(c0 + 2) * HW + w];
            float v3 = hrow[(c0 + 3) * HW + w];
            *(float4*)&lds_h[w * CIN + (c0 ^ swz)] = make_float4(v0, v1, v2, v3);
        }
    }
    __syncthreads();

    // acc_u: belongs at w+1 (shfl_up at end); acc_c: center; acc_d: at w-1.
    float acc_u[4] = {0.f, 0.f, 0.f, 0.f};
    float acc_c[4] = {0.f, 0.f, 0.f, 0.f};
    float acc_d[4] = {0.f, 0.f, 0.f, 0.f};

    // ---- input-to-state: taps (t0 -> x[w-1], t1 -> x[w]) ----
    {
        const float* wis = Wis_p + (size_t)hch * CIN * 8;   // SGPR base
#pragma unroll 4
        for (int cq = 0; cq < CIN; cq += 4) {
            float4 xv = *(const float4*)&lds_x[w * CIN + (cq ^ swz)];
            const float* wp = wis + cq * 8;
            float xa[4] = {xv.x, xv.y, xv.z, xv.w};
#pragma unroll
            for (int k = 0; k < 4; ++k)
#pragma unroll
                for (int g = 0; g < 4; ++g) {
                    acc_u[g] = fmaf(wp[k * 8 + g * 2 + 0], xa[k], acc_u[g]);
                    acc_c[g] = fmaf(wp[k * 8 + g * 2 + 1], xa[k], acc_c[g]);
                }
        }
    }

    // ---- state-to-state: taps (t0 -> h[w-1], t1 -> h[w], t2 -> h[w+1]) ----
    if (r > 0) {
        const float* wss = Wss_p + (size_t)hch * CIN * 12;  // SGPR base
#pragma unroll 4
        for (int cq = 0; cq < CIN; cq += 4) {
            float4 hv = *(const float4*)&lds_h[w * CIN + (cq ^ swz)];
            const float* wp = wss + cq * 12;
            float ha[4] = {hv.x, hv.y, hv.z, hv.w};
#pragma unroll
            for (int k = 0; k < 4; ++k)
#pragma unroll
                for (int g = 0; g < 4; ++g) {
                    acc_u[g] = fmaf(wp[k * 12 + g * 3 + 0], ha[k], acc_u[g]);
                    acc_c[g] = fmaf(wp[k * 12 + g * 3 + 1], ha[k], acc_c[g]);
                    acc_d[g] = fmaf(wp[k * 12 + g * 3 + 2], ha[k], acc_d[g]);
                }
        }
    }

    // ---- combine taps: 2 shuffles per gate ----
    float z[4];
#pragma unroll
    for (int g = 0; g < 4; ++g) {
        float zu = __shfl_up(acc_u[g], 1);    // S0 evaluated at w-1
        if (w == 0) zu = 0.0f;
        float zd = __shfl_down(acc_d[g], 1);  // S2 evaluated at w+1
        if (w == 63) zd = 0.0f;
        z[g] = acc_c[g] + zu + zd + bias_p[hch * 4 + g];
    }

    // ---- LSTM update ----
    float ig = 1.0f / (1.0f + __expf(-z[0]));
    float fg = 1.0f / (1.0f + __expf(-z[1]));
    float og = 1.0f / (1.0f + __expf(-z[2]));
    float gg = tanhf(z[3]);

    size_t cidx = ((size_t)b * HID + hch) * WDIM + w;
    float cold = (r == 0) ? 0.0f : c_state[cidx];
    float cnew = fg * cold + ig * gg;
    c_state[cidx] = cnew;
    out[((size_t)b * HID + hch) * HW + (size_t)r * WDIM + w] = og * tanhf(cnew);
}

extern "C" void kernel_launch(void* const* d_in, const int* in_sizes, int n_in,
                              void* d_out, int out_size, void* d_ws, size_t ws_size,
                              hipStream_t stream) {
    const float* x    = (const float*)d_in[0];
    const float* W_is = (const float*)d_in[1];
    const float* b_is = (const float*)d_in[2];
    const float* W_ss = (const float*)d_in[3];
    const float* b_ss = (const float*)d_in[4];
    float* out = (float*)d_out;
    float* ws  = (float*)d_ws;

    // ws layout (floats): c_state[131072] | Wis_p[131072] | Wss_p[196608] | bias_p[512]
    float* c_state = ws;
    float* Wis_p   = ws + 131072;
    float* Wss_p   = ws + 131072 + 131072;
    float* bias_p  = ws + 131072 + 131072 + 196608;

    pack_kernel<<<(HID * CIN * 4 * 3 + 255) / 256, 256, 0, stream>>>(
        W_is, b_is, W_ss, b_ss, Wis_p, Wss_p, bias_p);

    for (int r = 0; r < HDIM; ++r) {
        row_kernel<<<512, 256, 0, stream>>>(
            x, Wis_p, Wss_p, bias_p, c_state, out, r);
    }
}

// Round 5
// 1012.451 us; speedup vs baseline: 3.1028x; 1.1969x over previous
//
#include <hip/hip_runtime.h>
#include <math.h>

#define BATCH 16
#define CIN   128
#define HID   128
#define HDIM  64
#define WDIM  64
#define HW    4096
#define KTOT  640      // K = 256 (x: 2 causal taps x 128c) + 384 (h: 3 taps x 128c)
#define NTOT  512      // N = 4 gates x 128 hid, gate-major (o = g*128 + h)
#define LDSROW 136     // shorts per LDS row: 128 c + 8 pad -> 272 B stride, bank step 4

typedef short short8 __attribute__((ext_vector_type(8)));
typedef float f32x4  __attribute__((ext_vector_type(4)));

__device__ __forceinline__ unsigned short f2bf(float f) {
    union { float f; unsigned int u; } v; v.f = f;
    unsigned int r = v.u + 0x7fffu + ((v.u >> 16) & 1u);   // RNE
    return (unsigned short)(r >> 16);
}
__device__ __forceinline__ float sigm(float x)  { return 1.0f / (1.0f + __expf(-x)); }
__device__ __forceinline__ float tanhft(float x){ return 2.0f / (1.0f + __expf(-2.0f * x)) - 1.0f; }

// ---------------------------------------------------------------------------
// Pack: Wpk[o][k] bf16, k = (x: t*128+c for t in {0,1}) | (h: 256 + t*128+c).
// B-frag (16x16x32): lane reads 8 consecutive k at fixed o -> k-contiguous pack.
// bias_p[o] = b_is[o] + b_ss[o].
// ---------------------------------------------------------------------------
__global__ void pack_kernel(const float* __restrict__ W_is,
                            const float* __restrict__ b_is,
                            const float* __restrict__ W_ss,
                            const float* __restrict__ b_ss,
                            unsigned short* __restrict__ Wpk,
                            float* __restrict__ bias_p) {
    int idx = blockIdx.x * blockDim.x + threadIdx.x;
    if (idx < NTOT * KTOT) {
        int n = idx / KTOT;
        int k = idx - n * KTOT;
        float v;
        if (k < 256) {                       // masked x-conv: taps 0,1 only
            int t = k >> 7, c = k & 127;
            v = W_is[((size_t)n * CIN + c) * 3 + t];
        } else {                             // h-conv: taps 0,1,2
            int kk = k - 256;
            int t = kk >> 7, c = kk & 127;
            v = W_ss[((size_t)n * HID + c) * 3 + t];
        }
        Wpk[idx] = f2bf(v);
    }
    if (idx < NTOT) bias_p[idx] = b_is[idx] + b_ss[idx];
}

// ---------------------------------------------------------------------------
// Row kernel v5: one LSTM row as bf16 MFMA GEMM.
// Grid 64 blocks x 256 thr. block = (b, h-quarter of 32); wave = 2 m-tiles
// (32 of 64 w) x 4 gate n-tiles (same 16 h). K-step (32 k, const tap t):
//   A-frag = ds_read_b128 of 8 consecutive c at row (w + t - 1)  [halo zeros]
//   B-frag = global dwordx4 from Wpk (L2-hot, vmcnt-pipelined with MFMA)
// C/D layout (verified m89/m91): col=lane&15 -> h, row=quad*4+reg -> w, so all
// 4 gates of (w,h) are lane-local -> in-register LSTM epilogue, float4 stores.
// ---------------------------------------------------------------------------
__global__ __launch_bounds__(256) void row_kernel(
        const float* __restrict__ x,
        const unsigned short* __restrict__ Wpk,
        const float* __restrict__ bias_p,
        float* __restrict__ c_state,
        float* __restrict__ out,
        int r) {
    __shared__ __align__(16) unsigned short lds_x[66 * LDSROW];  // rows w_eff+1, 0..65
    __shared__ __align__(16) unsigned short lds_h[66 * LDSROW];

    const int tid  = threadIdx.x;
    const int b    = blockIdx.x >> 2;          // 0..15
    const int hq   = blockIdx.x & 3;           // h-quarter
    const int wv   = tid >> 6;                 // wave 0..3
    const int mh   = wv & 1;                   // m-half: m-tiles {2mh, 2mh+1}
    const int h16  = hq * 32 + (wv >> 1) * 16; // 16-h group
    const int lane = tid & 63;
    const int quad = lane >> 4;
    const int l15  = lane & 15;

    // zero halo rows (row 0 = w_eff -1; lds_h row 65 = w_eff 64)
    if (tid < 68) {
        ((unsigned int*)lds_x)[tid] = 0;
        ((unsigned int*)lds_h)[tid] = 0;
        ((unsigned int*)lds_h)[65 * 68 + tid] = 0;
    }

    // ---- stage x row r -> bf16 LDS [w+1][c] (pair c's into one b32 write) ----
    {
        const float* xrow = x + (size_t)b * CIN * HW + (size_t)r * WDIM;
#pragma unroll
        for (int p = 0; p < 16; ++p) {
            int flat = p * 256 + tid;          // 0..4095
            int w  = flat & 63;                // coalesced along w
            int cp = flat >> 6;                // c-pair 0..63
            float v0 = xrow[(2 * cp    ) * HW + w];
            float v1 = xrow[(2 * cp + 1) * HW + w];
            unsigned int word = (unsigned int)f2bf(v0) | ((unsigned int)f2bf(v1) << 16);
            ((unsigned int*)lds_x)[(w + 1) * 68 + cp] = word;
        }
    }
    // ---- stage h row r-1 (previous launch's out) ----
    if (r > 0) {
        const float* hrow = out + (size_t)b * HID * HW + (size_t)(r - 1) * WDIM;
#pragma unroll
        for (int p = 0; p < 16; ++p) {
            int flat = p * 256 + tid;
            int w  = flat & 63;
            int cp = flat >> 6;
            float v0 = hrow[(2 * cp    ) * HW + w];
            float v1 = hrow[(2 * cp + 1) * HW + w];
            unsigned int word = (unsigned int)f2bf(v0) | ((unsigned int)f2bf(v1) << 16);
            ((unsigned int*)lds_h)[(w + 1) * 68 + cp] = word;
        }
    }
    __syncthreads();

    f32x4 acc[2][4];
#pragma unroll
    for (int i = 0; i < 2; ++i)
#pragma unroll
        for (int g = 0; g < 4; ++g) acc[i][g] = (f32x4){0.f, 0.f, 0.f, 0.f};

    // B base: n = g*128 + h16 + l15, k = ks*32 + quad*8 + j (j contiguous)
    const unsigned short* wb = Wpk + (size_t)(h16 + l15) * KTOT + quad * 8;
    // A lane offset: row (mt*16 + l15 + t), col c0 + quad*8
    const int a_off = l15 * LDSROW + quad * 8;

    // ---- x part: k-steps 0..7 (t = ks>>2, c0 = (ks&3)*32) ----
#pragma unroll
    for (int ks = 0; ks < 8; ++ks) {
        const int t = ks >> 2, c0 = (ks & 3) * 32;
        short8 a0 = *(const short8*)&lds_x[(mh * 32 +      t) * LDSROW + c0 + a_off];
        short8 a1 = *(const short8*)&lds_x[(mh * 32 + 16 + t) * LDSROW + c0 + a_off];
#pragma unroll
        for (int g = 0; g < 4; ++g) {
            short8 bf = *(const short8*)&wb[(size_t)g * (128 * KTOT) + ks * 32];
            acc[0][g] = __builtin_amdgcn_mfma_f32_16x16x32_bf16(a0, bf, acc[0][g], 0, 0, 0);
            acc[1][g] = __builtin_amdgcn_mfma_f32_16x16x32_bf16(a1, bf, acc[1][g], 0, 0, 0);
        }
    }
    // ---- h part: k-steps 8..19 ----
    if (r > 0) {
#pragma unroll
        for (int ks = 0; ks < 12; ++ks) {
            const int t = ks >> 2, c0 = (ks & 3) * 32;
            short8 a0 = *(const short8*)&lds_h[(mh * 32 +      t) * LDSROW + c0 + a_off];
            short8 a1 = *(const short8*)&lds_h[(mh * 32 + 16 + t) * LDSROW + c0 + a_off];
#pragma unroll
            for (int g = 0; g < 4; ++g) {
                short8 bf = *(const short8*)&wb[(size_t)g * (128 * KTOT) + (8 + ks) * 32];
                acc[0][g] = __builtin_amdgcn_mfma_f32_16x16x32_bf16(a0, bf, acc[0][g], 0, 0, 0);
                acc[1][g] = __builtin_amdgcn_mfma_f32_16x16x32_bf16(a1, bf, acc[1][g], 0, 0, 0);
            }
        }
    }

    // ---- epilogue: gates are lane-local across the 4 n-tiles ----
    const int hch = h16 + l15;
    const float bi = bias_p[      hch];
    const float bf_= bias_p[128 + hch];
    const float bo = bias_p[256 + hch];
    const float bg = bias_p[384 + hch];

#pragma unroll
    for (int mi = 0; mi < 2; ++mi) {
        const int w0 = (mh * 2 + mi) * 16 + quad * 4;     // reg -> consecutive w
        float* cs = c_state + ((size_t)b * HID + hch) * WDIM + w0;
        f32x4 cold;
        if (r == 0) cold = (f32x4){0.f, 0.f, 0.f, 0.f};
        else        cold = *(const f32x4*)cs;
        f32x4 hv;
#pragma unroll
        for (int e = 0; e < 4; ++e) {
            float zi = acc[mi][0][e] + bi;
            float zf = acc[mi][1][e] + bf_;
            float zo = acc[mi][2][e] + bo;
            float zg = acc[mi][3][e] + bg;
            float ig = sigm(zi), fg = sigm(zf), og = sigm(zo);
            float gg = tanhft(zg);
            float cn = fg * cold[e] + ig * gg;
            cold[e] = cn;
            hv[e]   = og * tanhft(cn);
        }
        *(f32x4*)cs = cold;
        *(f32x4*)&out[(((size_t)b * HID + hch) * HDIM + r) * WDIM + w0] = hv;
    }
}

extern "C" void kernel_launch(void* const* d_in, const int* in_sizes, int n_in,
                              void* d_out, int out_size, void* d_ws, size_t ws_size,
                              hipStream_t stream) {
    const float* x    = (const float*)d_in[0];
    const float* W_is = (const float*)d_in[1];
    const float* b_is = (const float*)d_in[2];
    const float* W_ss = (const float*)d_in[3];
    const float* b_ss = (const float*)d_in[4];
    float* out = (float*)d_out;

    // ws: c_state fp32[131072] | Wpk bf16[512*640] | bias fp32[512]
    float*          c_state = (float*)d_ws;
    unsigned short* Wpk     = (unsigned short*)((char*)d_ws + 524288);
    float*          bias_p  = (float*)((char*)d_ws + 524288 + 655360);

    pack_kernel<<<(NTOT * KTOT + 255) / 256, 256, 0, stream>>>(
        W_is, b_is, W_ss, b_ss, Wpk, bias_p);

    for (int r = 0; r < HDIM; ++r) {
        row_kernel<<<64, 256, 0, stream>>>(x, Wpk, bias_p, c_state, out, r);
    }
}